// Round 6
// baseline (422.188 us; speedup 1.0000x reference)
//
#include <hip/hip_runtime.h>
#include <math.h>

#define NB 4096
#define NH 3
#define NK 32768
#define ND 128
#define KA 256           // A stored K: [rh(128) | rl(128)]
#define KB 256           // B stored K: [wh(128) | wl(128)]  (dedup: wh read twice via regs)
#define RB 64            // rows per block
#define CS 16            // column splits (2 per XCD). CS=32 measured worse (117.5 vs 108).
#define CPB (NK / CS)    // 2048 cols per block
#define CI 256           // cols per col-iteration (4 waves x 64)
#define NCI (CPB / CI)   // 8 col-iterations per block

typedef _Float16 half8_t __attribute__((ext_vector_type(8)));
typedef _Float16 half2_t __attribute__((ext_vector_type(2)));
typedef float f32x4 __attribute__((ext_vector_type(4)));
typedef __attribute__((address_space(1))) const unsigned int gu32_t;
typedef __attribute__((address_space(3))) unsigned int lu32_t;

// ---------------------------------------------------------------------------
// init: resid = inputs, quantized = 0, loss = 0, rr = sum(resid^2), Aext row.
__global__ __launch_bounds__(64) void init_kernel(const float* __restrict__ inp,
                                                  float* __restrict__ resid,
                                                  float* __restrict__ rr,
                                                  float* __restrict__ out,
                                                  _Float16* __restrict__ Aext) {
  int row = blockIdx.x;
  int lane = threadIdx.x;
  const float2* ip = (const float2*)(inp + row * ND);
  float2 v = ip[lane];
  ((float2*)(resid + row * ND))[lane] = v;
  ((float2*)(out + NB + row * ND))[lane] = make_float2(0.f, 0.f);
  if (lane == 0) out[row] = 0.f; // loss
  _Float16 h0 = (_Float16)v.x, h1 = (_Float16)v.y;
  _Float16 l0 = (_Float16)(v.x - (float)h0), l1 = (_Float16)(v.y - (float)h1);
  half2_t h = {h0, h1}, l = {l0, l1};
  _Float16* base = Aext + (size_t)row * KA;
  *(half2_t*)(base + 2 * lane) = h;       // rh
  *(half2_t*)(base + 128 + 2 * lane) = l; // rl
  float s = v.x * v.x + v.y * v.y;
  #pragma unroll
  for (int m = 32; m; m >>= 1) s += __shfl_xor(s, m, 64);
  if (lane == 0) rr[row] = s;
}

// ---------------------------------------------------------------------------
// norms[row] = sum(W[row]^2) for all H*K rows (one wave per row), fp32 exact.
// NOTE: do NOT change this reduction tree — its rounding order is what the
// reference-matching argmax ties were validated against.
__global__ __launch_bounds__(256) void norms_kernel(const float* __restrict__ emb,
                                                    float* __restrict__ norms) {
  int row = blockIdx.x * 4 + (threadIdx.x >> 6);
  int lane = threadIdx.x & 63;
  const float2* wp = (const float2*)(emb + (size_t)row * ND);
  float2 v = wp[lane];
  float s = v.x * v.x + v.y * v.y;
  #pragma unroll
  for (int m = 32; m; m >>= 1) s += __shfl_xor(s, m, 64);
  if (lane == 0) norms[row] = s;
}

// ---------------------------------------------------------------------------
// fp32 -> (hi,lo) fp16 split, ALL heads at once (emb is static), into
// kstep-major fragment layout WITHOUT the wh duplicate:
//   f16 offset = head*NK*KB + col64*16384 + ks*2048 + tn*512 + klo*128 + n_lo*8 + j
// ks 0..3 = wh chunks (k 0..127), ks 4..7 = wl chunks. A wave's 4 tn
// fragments of one ks are at byte offsets 0/1024/2048/3072 (imm-addressable).
__global__ __launch_bounds__(256) void split_w_all_kernel(const float* __restrict__ emb,
                                                          _Float16* __restrict__ Bext) {
  const int head = blockIdx.x >> 11;      // 0..2
  const int cg = blockIdx.x & 2047;       // col group 0..2047 (16 cols each)
  const int n_lo = threadIdx.x & 15;
  const int c = threadIdx.x >> 4;         // 8-elem k-chunk 0..15 (k = c*8..)
  const int n = cg * 16 + n_lo;

  const float4* wp = (const float4*)(emb + (size_t)head * NK * ND + (size_t)n * ND + c * 8);
  float4 v0 = wp[0], v1 = wp[1];
  float xv[8] = {v0.x, v0.y, v0.z, v0.w, v1.x, v1.y, v1.z, v1.w};
  half8_t h, l;
  #pragma unroll
  for (int j = 0; j < 8; ++j) {
    _Float16 hh = (_Float16)xv[j];
    h[j] = hh;
    l[j] = (_Float16)(xv[j] - (float)hh);
  }
  const int ks0 = c >> 2; // 32-k chunk 0..3
  const int klo = c & 3;  // 8-chunk within the 32-k step
  _Float16* base = Bext + (size_t)head * NK * KB + (size_t)(cg >> 2) * 16384 +
                   (cg & 3) * 512 + klo * 128 + n_lo * 8;
  *(half8_t*)(base + ks0 * 2048) = h;       // wh  (ks 0..3)
  *(half8_t*)(base + (4 + ks0) * 2048) = l; // wl  (ks 4..7)
}

// ---------------------------------------------------------------------------
// Barrier-free score kernel — R0-verified structure (no spills; fold
// immediately follows the kc loop so acc is DEAD at the ci backedge —
// R2/R4 lesson: any schedule keeping acc or bs/bi live across a long phase
// spills catastrophically). Occupancy is hard-capped at 2-3 waves/SIMD by
// the ~168 reg/wave requirement; the lever is DESYNC of co-resident waves.
// R5 evidence: in-phase cost model (MFMA 2x3725 + VALU serialized 2x2750 +
// unhidden stalls ~= 16k cy/ci) matches the measured 16,200 cy ci period
// exactly; R5's skew step (1280cy = 8% of period) was too small to test the
// theory. This round: step = 6016cy (37% of ci period, s_sleep(94)) per
// dispatch round (bid>>8). Co-resident blocks are (b, b+256[, b+512]):
// same XCD (256%8==0), same CU slot under round-robin, so consecutive
// bid>>8 are exactly the waves sharing a SIMD. s_setprio(1) kept around the
// MFMA cluster (T5: pays off once waves are actually out of phase).
// B dedup: per 32-k chunk kc, load 4 wh + 4 wl fragments ONCE; wh feeds TWO
// MFMA sets (A=rh, A=rl), wl one (A=rh).
// Running argmax in registers: descending order + ">=" == first-index tie.
// bid&15 = col-split; 2 x 1 MB B slices per XCD's L2 (cs mod 8 == xcd).
__global__ __launch_bounds__(256, 2) void score_mfma_kernel(
    const _Float16* __restrict__ Aext, const _Float16* __restrict__ Bext,
    const float* __restrict__ rr, const float* __restrict__ normh,
    float* __restrict__ partial_s, int* __restrict__ partial_i) {
  __shared__ __align__(16) _Float16 Ash[RB * KA]; // 32 KB

  const int bid = blockIdx.x;
  const int cs = bid & (CS - 1);
  const int rowb = bid >> 4;
  const int rowBase = rowb * RB;
  const int colBase0 = cs * CPB;

  const int tid = threadIdx.x;
  const int lane = tid & 63;
  const int wn = tid >> 6; // wave = col group 0..3
  const int l15 = lane & 15;
  const int q = lane >> 4;

  // ---- stage A panel [rh|rl] (once) ----
  {
    const int mrow = lane >> 3;             // 0..7 within 8-row group
    const int cg = (lane & 7) ^ (mrow & 7); // chunk this lane fetches
    #pragma unroll
    for (int i = 0; i < 8; ++i) {
      int wc = wn * 8 + i; // 0..31 wave-chunks (1 KB each)
      int p = wc >> 3;     // panel 0..3 (64 k each)
      int m0 = (wc & 7) * 8;
      const _Float16* gA = Aext + (size_t)(rowBase + m0 + mrow) * KA + p * 64 + cg * 8;
      __builtin_amdgcn_global_load_lds((gu32_t*)gA, (lu32_t*)&Ash[(p * 64 + m0) * 64], 16, 0, 0);
    }
  }

  // ---- start-skew v2: desync co-resident blocks (dispatch round = bid>>8).
  // Step = ~6016 cy = 37% of the 16,200cy ci period (R5's 1280cy step was 8%
  // of a period -> null, uninformative). A-staging is already in flight, so
  // its latency hides under the sleep. Max waste 3 x 6016cy ~= 7.5us on
  // last-round blocks; expected gain ~20us/dispatch if the lockstep theory
  // holds at proper amplitude.
  {
    const int skew = bid >> 8; // 0..3 for grid 1024
    for (int i = 0; i < skew; ++i) __builtin_amdgcn_s_sleep(94); // ~6016 cy
  }

  // per-lane A-fragment LDS byte addresses (2 kc parities x 4 m-tiles)
  int aaddr[2][4];
  #pragma unroll
  for (int par = 0; par < 2; ++par)
    #pragma unroll
    for (int mt = 0; mt < 4; ++mt) {
      int m = mt * 16 + l15;
      int slot = (par * 4 + q) ^ (m & 7);
      aaddr[par][mt] = (m * 8 + slot) * 16; // bytes
    }

  // per-lane rr values (row = mt*16 + q*4 + reg)
  float rv[16];
  #pragma unroll
  for (int mt = 0; mt < 4; ++mt)
    #pragma unroll
    for (int reg = 0; reg < 4; ++reg)
      rv[mt * 4 + reg] = rr[rowBase + mt * 16 + q * 4 + reg];

  float bs[16];
  int bi[16];
  #pragma unroll
  for (int t = 0; t < 16; ++t) { bs[t] = -INFINITY; bi[t] = 0x7fffffff; }

  __syncthreads(); // the only barrier before the epilogue

  #pragma unroll 1
  for (int ci = NCI - 1; ci >= 0; --ci) {
    const int ncol = colBase0 + ci * CI + wn * 64;
    // 32-bit f16-index vs uniform Bext base (saddr + voffset + imm)
    const unsigned int boff = (unsigned int)(ncol >> 6) * 16384u + (unsigned int)lane * 8u;

    f32x4 acc[4][4];
    #pragma unroll
    for (int i = 0; i < 4; ++i)
      #pragma unroll
      for (int j = 0; j < 4; ++j) acc[i][j] = (f32x4){0.f, 0.f, 0.f, 0.f};

    #pragma unroll 2
    for (int kc = 0; kc < 4; ++kc) {
      half8_t bh[4], bl[4];
      #pragma unroll
      for (int tn = 0; tn < 4; ++tn) {
        bh[tn] = *(const half8_t*)(Bext + boff + (unsigned int)(kc * 2048 + tn * 512));
        bl[tn] = *(const half8_t*)(Bext + boff + (unsigned int)((4 + kc) * 2048 + tn * 512));
      }
      const int par = kc & 1, p = kc >> 1;
      half8_t afh[4], afl[4];
      #pragma unroll
      for (int mt = 0; mt < 4; ++mt) {
        afh[mt] = *(const half8_t*)((const char*)Ash + aaddr[par][mt] + p * 8192);
        afl[mt] = *(const half8_t*)((const char*)Ash + aaddr[par][mt] + 16384 + p * 8192);
      }
      __builtin_amdgcn_s_setprio(1); // T5: favor the MFMA-phase wave
      #pragma unroll
      for (int mt = 0; mt < 4; ++mt)
        #pragma unroll
        for (int tn = 0; tn < 4; ++tn)
          acc[mt][tn] = __builtin_amdgcn_mfma_f32_16x16x32_f16(afh[mt], bh[tn], acc[mt][tn], 0, 0, 0);
      #pragma unroll
      for (int mt = 0; mt < 4; ++mt)
        #pragma unroll
        for (int tn = 0; tn < 4; ++tn)
          acc[mt][tn] = __builtin_amdgcn_mfma_f32_16x16x32_f16(afl[mt], bh[tn], acc[mt][tn], 0, 0, 0);
      #pragma unroll
      for (int mt = 0; mt < 4; ++mt)
        #pragma unroll
        for (int tn = 0; tn < 4; ++tn)
          acc[mt][tn] = __builtin_amdgcn_mfma_f32_16x16x32_f16(afh[mt], bl[tn], acc[mt][tn], 0, 0, 0);
      __builtin_amdgcn_s_setprio(0);
    }

    // fold into running argmax; tn DESCENDING + ci descending => cols visited
    // in strictly decreasing order, so `>=` keeps the lowest index on ties.
    #pragma unroll
    for (int tn = 3; tn >= 0; --tn) {
      float nw = normh[ncol + tn * 16 + l15];
      int cidx = ncol + tn * 16 + l15;
      #pragma unroll
      for (int mt = 0; mt < 4; ++mt) {
        #pragma unroll
        for (int reg = 0; reg < 4; ++reg) {
          const int s = mt * 4 + reg;
          float t1 = rv[s] + nw;                       // fl(rr + |w|^2), as ref
          float v = fmaf(2.0f, acc[mt][tn][reg], -t1); // == fl(2*acc - t1)
          if (v >= bs[s]) { bs[s] = v; bi[s] = cidx; }
        }
      }
    }
  }

  // ---- block argmax reduction (overlay scratch on Ash) ----
  __syncthreads(); // all LDS A-reads complete
  float* red_s = (float*)Ash;      // [64][4]
  int* red_i = (int*)Ash + RB * 4; // [64][4]
  #pragma unroll
  for (int t = 0; t < 16; ++t) {
    float s = bs[t];
    int ii = bi[t];
    #pragma unroll
    for (int mask = 1; mask <= 8; mask <<= 1) {
      float os = __shfl_xor(s, mask, 64);
      int oi = __shfl_xor(ii, mask, 64);
      if (os > s || (os == s && oi < ii)) { s = os; ii = oi; }
    }
    if (l15 == 0) {
      int rloc = (t >> 2) * 16 + q * 4 + (t & 3); // mt*16 + q*4 + reg
      red_s[rloc * 4 + wn] = s;
      red_i[rloc * 4 + wn] = ii;
    }
  }
  __syncthreads();
  if (tid < RB) {
    float s0 = red_s[tid * 4];
    int i0 = red_i[tid * 4];
    #pragma unroll
    for (int x = 1; x < 4; ++x) {
      float sx = red_s[tid * 4 + x];
      int ix = red_i[tid * 4 + x];
      if (sx > s0 || (sx == s0 && ix < i0)) { s0 = sx; i0 = ix; }
    }
    partial_s[(size_t)(rowBase + tid) * CS + cs] = s0;
    partial_i[(size_t)(rowBase + tid) * CS + cs] = i0;
  }
}

// ---------------------------------------------------------------------------
// Combine col-split partials -> code; resid -= W[c]; quantized += W[c];
// new rr; Aext row for next head.
__global__ __launch_bounds__(64) void reduce_update_kernel(const float* __restrict__ embh,
                                                           float* __restrict__ resid,
                                                           float* __restrict__ rr,
                                                           const float* __restrict__ ps,
                                                           const int* __restrict__ pi,
                                                           float* __restrict__ out,
                                                           _Float16* __restrict__ Aext, int h) {
  int row = blockIdx.x;
  int lane = threadIdx.x;
  float bs = -INFINITY;
  int bi = 0x7fffffff;
  if (lane < CS) {
    bs = ps[(size_t)row * CS + lane];
    bi = pi[(size_t)row * CS + lane];
  }
  #pragma unroll
  for (int m = 8; m; m >>= 1) {
    float os = __shfl_xor(bs, m, 64);
    int oi = __shfl_xor(bi, m, 64);
    if (os > bs || (os == bs && oi < bi)) { bs = os; bi = oi; }
  }
  int c = __shfl(bi, 0, 64);
  if (lane == 0) out[NB + NB * ND + row * NH + h] = (float)c; // codes as f32

  const float* wv = embh + (size_t)c * ND;
  float q0 = wv[lane], q1 = wv[lane + 64];
  float r0 = resid[row * ND + lane] - q0;
  float r1 = resid[row * ND + lane + 64] - q1;
  resid[row * ND + lane] = r0;
  resid[row * ND + lane + 64] = r1;
  out[NB + row * ND + lane] += q0;
  out[NB + row * ND + lane + 64] += q1;

  // Aext row for the next head (harmless extra work on the last head)
  _Float16 h0 = (_Float16)r0, l0 = (_Float16)(r0 - (float)h0);
  _Float16 h1 = (_Float16)r1, l1 = (_Float16)(r1 - (float)h1);
  _Float16* ab = Aext + (size_t)row * KA;
  ab[lane] = h0;       ab[lane + 64] = h1;       // rh
  ab[128 + lane] = l0; ab[128 + lane + 64] = l1; // rl

  float s = r0 * r0 + r1 * r1;
  #pragma unroll
  for (int m = 32; m; m >>= 1) s += __shfl_xor(s, m, 64);
  if (lane == 0) rr[row] = s;
}

// ---------------------------------------------------------------------------
extern "C" void kernel_launch(void* const* d_in, const int* in_sizes, int n_in,
                              void* d_out, int out_size, void* d_ws, size_t ws_size,
                              hipStream_t stream) {
  const float* inp = (const float*)d_in[0]; // (4096,1,128)
  const float* emb = (const float*)d_in[1]; // (3,32768,128)
  float* out = (float*)d_out;               // loss | quantized | codes

  float* resid = (float*)d_ws;                        // NB*ND f32
  float* rr = resid + NB * ND;                        // NB
  float* norms = rr + NB;                             // NH*NK
  float* ps = norms + NH * NK;                        // NB*CS f32
  int* pi = (int*)(ps + (size_t)NB * CS);             // NB*CS i32
  _Float16* Aext = (_Float16*)(pi + (size_t)NB * CS); // NB*KA f16
  _Float16* Bext = Aext + (size_t)NB * KA;            // NH*NK*KB f16 (~50 MB)

  hipLaunchKernelGGL(init_kernel, dim3(NB), dim3(64), 0, stream, inp, resid, rr, out, Aext);
  hipLaunchKernelGGL(norms_kernel, dim3(NH * NK / 4), dim3(256), 0, stream, emb, norms);
  hipLaunchKernelGGL(split_w_all_kernel, dim3(NH * NK / 16), dim3(256), 0, stream, emb, Bext);
  for (int h = 0; h < NH; ++h) {
    hipLaunchKernelGGL(score_mfma_kernel, dim3((NB / RB) * CS), dim3(256), 0, stream,
                       Aext, Bext + (size_t)h * NK * KB, rr, norms + (size_t)h * NK, ps, pi);
    hipLaunchKernelGGL(reduce_update_kernel, dim3(NB), dim3(64), 0, stream,
                       emb + (size_t)h * NK * ND, resid, rr, ps, pi, out, Aext, h);
  }
}

// Round 7
// 416.883 us; speedup vs baseline: 1.0127x; 1.0127x over previous
//
#include <hip/hip_runtime.h>
#include <math.h>

#define NB 4096
#define NH 3
#define NK 32768
#define ND 128
#define KA 256           // A stored K: [rh(128) | rl(128)]
#define KB 256           // B stored K: [wh(128) | wl(128)]  (dedup: wh read twice via regs)
#define RB 128           // rows per block (128: halves B read amplification vs 64)
#define CS 16            // column splits (2 per XCD). CS=32 measured worse (117.5 vs 108).
#define CPB (NK / CS)    // 2048 cols per block
#define CI 128           // cols per col-iteration (4 waves x 32)
#define NCI (CPB / CI)   // 16 col-iterations per block

typedef _Float16 half8_t __attribute__((ext_vector_type(8)));
typedef _Float16 half2_t __attribute__((ext_vector_type(2)));
typedef float f32x4 __attribute__((ext_vector_type(4)));
typedef __attribute__((address_space(1))) const unsigned int gu32_t;
typedef __attribute__((address_space(3))) unsigned int lu32_t;

// ---------------------------------------------------------------------------
// init: resid = inputs, quantized = 0, loss = 0, rr = sum(resid^2), Aext row.
__global__ __launch_bounds__(64) void init_kernel(const float* __restrict__ inp,
                                                  float* __restrict__ resid,
                                                  float* __restrict__ rr,
                                                  float* __restrict__ out,
                                                  _Float16* __restrict__ Aext) {
  int row = blockIdx.x;
  int lane = threadIdx.x;
  const float2* ip = (const float2*)(inp + row * ND);
  float2 v = ip[lane];
  ((float2*)(resid + row * ND))[lane] = v;
  ((float2*)(out + NB + row * ND))[lane] = make_float2(0.f, 0.f);
  if (lane == 0) out[row] = 0.f; // loss
  _Float16 h0 = (_Float16)v.x, h1 = (_Float16)v.y;
  _Float16 l0 = (_Float16)(v.x - (float)h0), l1 = (_Float16)(v.y - (float)h1);
  half2_t h = {h0, h1}, l = {l0, l1};
  _Float16* base = Aext + (size_t)row * KA;
  *(half2_t*)(base + 2 * lane) = h;       // rh
  *(half2_t*)(base + 128 + 2 * lane) = l; // rl
  float s = v.x * v.x + v.y * v.y;
  #pragma unroll
  for (int m = 32; m; m >>= 1) s += __shfl_xor(s, m, 64);
  if (lane == 0) rr[row] = s;
}

// ---------------------------------------------------------------------------
// norms[row] = sum(W[row]^2) for all H*K rows (one wave per row), fp32 exact.
// NOTE: do NOT change this reduction tree — its rounding order is what the
// reference-matching argmax ties were validated against.
__global__ __launch_bounds__(256) void norms_kernel(const float* __restrict__ emb,
                                                    float* __restrict__ norms) {
  int row = blockIdx.x * 4 + (threadIdx.x >> 6);
  int lane = threadIdx.x & 63;
  const float2* wp = (const float2*)(emb + (size_t)row * ND);
  float2 v = wp[lane];
  float s = v.x * v.x + v.y * v.y;
  #pragma unroll
  for (int m = 32; m; m >>= 1) s += __shfl_xor(s, m, 64);
  if (lane == 0) norms[row] = s;
}

// ---------------------------------------------------------------------------
// fp32 -> (hi,lo) fp16 split, ALL heads at once (emb is static), into
// kstep-major fragment layout WITHOUT the wh duplicate:
//   f16 offset = head*NK*KB + col64*16384 + ks*2048 + tn*512 + klo*128 + n_lo*8 + j
// ks 0..3 = wh chunks (k 0..127), ks 4..7 = wl chunks. Fragments of one ks
// for adjacent 16-col subtiles are at byte offsets 0/512/1024/1536.
__global__ __launch_bounds__(256) void split_w_all_kernel(const float* __restrict__ emb,
                                                          _Float16* __restrict__ Bext) {
  const int head = blockIdx.x >> 11;      // 0..2
  const int cg = blockIdx.x & 2047;       // col group 0..2047 (16 cols each)
  const int n_lo = threadIdx.x & 15;
  const int c = threadIdx.x >> 4;         // 8-elem k-chunk 0..15 (k = c*8..)
  const int n = cg * 16 + n_lo;

  const float4* wp = (const float4*)(emb + (size_t)head * NK * ND + (size_t)n * ND + c * 8);
  float4 v0 = wp[0], v1 = wp[1];
  float xv[8] = {v0.x, v0.y, v0.z, v0.w, v1.x, v1.y, v1.z, v1.w};
  half8_t h, l;
  #pragma unroll
  for (int j = 0; j < 8; ++j) {
    _Float16 hh = (_Float16)xv[j];
    h[j] = hh;
    l[j] = (_Float16)(xv[j] - (float)hh);
  }
  const int ks0 = c >> 2; // 32-k chunk 0..3
  const int klo = c & 3;  // 8-chunk within the 32-k step
  _Float16* base = Bext + (size_t)head * NK * KB + (size_t)(cg >> 2) * 16384 +
                   (cg & 3) * 512 + klo * 128 + n_lo * 8;
  *(half8_t*)(base + ks0 * 2048) = h;       // wh  (ks 0..3)
  *(half8_t*)(base + (4 + ks0) * 2048) = l; // wl  (ks 4..7)
}

// ---------------------------------------------------------------------------
// Barrier-free score kernel — RB=128 restructure. The R10 model: legs are
// {MFMA floor ~50us, per-CU L2 B-stream ~31us, fold VALU} partially
// serialized. B read amplification = NB/RB per column; RB 64->128 halves
// the L2 leg (1 GB -> 512 MB/dispatch), each B byte now feeds 2x MFMAs
// (B loads/kc/wave 8->4). Grid 512 = exactly 2 blocks/CU, tail-free.
// Register discipline (R2/R4 lessons: spills are the #1 failure mode):
//  - acc[8][2] = 64 regs, DEAD at the ci backedge (fold right after kc loop)
//  - A-frags read PER-MT (8 transient VGPRs, not 64)
//  - rr in a 512B LDS panel (read transiently per fold), not 32 regs
//  - aaddr compressed to 8 regs: odd-kc address == even-kc address XOR 64
//    (slot=(par*4+q)^(m&7); par flips slot bit2 -> byte bit6, carry-free)
// Persistent: bs/bi 64 + aaddr0 8 + misc ~12 => ~130 VGPR peak, no spill
// at (256,2). R6 lesson: start-skew removed (hurt at proper amplitude);
// setprio kept (neutral-to-positive, T5).
// Running argmax in registers: ci desc + tn desc => cols strictly
// decreasing, ">=" keeps the lowest index on ties (matches jnp.argmax).
// bid&15 = col-split; 2 x 1 MB B slices per XCD's L2 (cs mod 8 == xcd).
__global__ __launch_bounds__(256, 2) void score_mfma_kernel(
    const _Float16* __restrict__ Aext, const _Float16* __restrict__ Bext,
    const float* __restrict__ rr, const float* __restrict__ normh,
    float* __restrict__ partial_s, int* __restrict__ partial_i) {
  __shared__ __align__(16) _Float16 Ash[RB * KA]; // 64 KB: [p:4][m:128][slot:8][8 f16]
  __shared__ __align__(16) float rrsh[RB];        // 512 B

  const int bid = blockIdx.x;
  const int cs = bid & (CS - 1);
  const int rowb = bid >> 4;
  const int rowBase = rowb * RB;
  const int colBase0 = cs * CPB;

  const int tid = threadIdx.x;
  const int lane = tid & 63;
  const int wn = tid >> 6; // wave = 32-col group 0..3
  const int l15 = lane & 15;
  const int q = lane >> 4;

  // ---- stage A panel [rh|rl] (once): wave wn stages panel p=wn ----
  // LDS[p][m][slot] = A[rowBase+m][p*64 + (slot^(m&7))*8 ..+8]
  {
    const int mrow = lane >> 3;             // 0..7 within 8-row group
    const int cg = (lane & 7) ^ (mrow & 7); // global chunk this lane fetches
    #pragma unroll
    for (int i = 0; i < 16; ++i) {
      const int m0 = i * 8; // 8-row group within the 128
      const _Float16* gA = Aext + (size_t)(rowBase + m0 + mrow) * KA + wn * 64 + cg * 8;
      __builtin_amdgcn_global_load_lds((gu32_t*)gA, (lu32_t*)&Ash[(wn * 128 + m0) * 64], 16, 0, 0);
    }
  }
  if (tid < RB) rrsh[tid] = rr[rowBase + tid];

  // per-lane A-fragment LDS byte addresses, even-kc parity (odd = ^64)
  int aaddr0[8];
  #pragma unroll
  for (int mt = 0; mt < 8; ++mt) {
    const int m = mt * 16 + l15;
    const int slot = q ^ (m & 7);
    aaddr0[mt] = (m * 8 + slot) * 16; // bytes within a p-panel
  }

  float bs[32];
  int bi[32];
  #pragma unroll
  for (int t = 0; t < 32; ++t) { bs[t] = -INFINITY; bi[t] = 0x7fffffff; }

  __syncthreads(); // the only barrier before the epilogue

  #pragma unroll 1
  for (int ci = NCI - 1; ci >= 0; --ci) {
    const int ncol = colBase0 + ci * CI + wn * 32; // wave's 32-col tile
    const unsigned int boff = (unsigned int)(ncol >> 6) * 16384u +
                              ((unsigned int)(ncol >> 4) & 3u) * 512u +
                              (unsigned int)lane * 8u;

    // normh for this ci, issued early so they overlap the MFMA phase
    float nw[2];
    #pragma unroll
    for (int tn = 0; tn < 2; ++tn) nw[tn] = normh[ncol + tn * 16 + l15];

    f32x4 acc[8][2];
    #pragma unroll
    for (int i = 0; i < 8; ++i) {
      acc[i][0] = (f32x4){0.f, 0.f, 0.f, 0.f};
      acc[i][1] = (f32x4){0.f, 0.f, 0.f, 0.f};
    }

    #pragma unroll 2
    for (int kc = 0; kc < 4; ++kc) {
      half8_t bh[2], bl[2];
      #pragma unroll
      for (int tn = 0; tn < 2; ++tn) {
        bh[tn] = *(const half8_t*)(Bext + boff + (unsigned int)(kc * 2048 + tn * 512));
        bl[tn] = *(const half8_t*)(Bext + boff + (unsigned int)((4 + kc) * 2048 + tn * 512));
      }
      const int axor = (kc & 1) << 6;        // odd-kc slot parity
      const int abase = (kc >> 1) * 16384;   // p-panel stride (128 rows x 128 B)
      __builtin_amdgcn_s_setprio(1); // T5: favor the MFMA-phase wave
      #pragma unroll
      for (int mt = 0; mt < 8; ++mt) {
        const char* ap = (const char*)Ash + ((aaddr0[mt] ^ axor) + abase);
        half8_t ah = *(const half8_t*)ap;             // rh frag
        half8_t al = *(const half8_t*)(ap + 32768);   // rl frag (p+2 panels)
        acc[mt][0] = __builtin_amdgcn_mfma_f32_16x16x32_f16(ah, bh[0], acc[mt][0], 0, 0, 0);
        acc[mt][1] = __builtin_amdgcn_mfma_f32_16x16x32_f16(ah, bh[1], acc[mt][1], 0, 0, 0);
        acc[mt][0] = __builtin_amdgcn_mfma_f32_16x16x32_f16(al, bh[0], acc[mt][0], 0, 0, 0);
        acc[mt][1] = __builtin_amdgcn_mfma_f32_16x16x32_f16(al, bh[1], acc[mt][1], 0, 0, 0);
        acc[mt][0] = __builtin_amdgcn_mfma_f32_16x16x32_f16(ah, bl[0], acc[mt][0], 0, 0, 0);
        acc[mt][1] = __builtin_amdgcn_mfma_f32_16x16x32_f16(ah, bl[1], acc[mt][1], 0, 0, 0);
      }
      __builtin_amdgcn_s_setprio(0);
    }

    // fold into running argmax; tn DESCENDING + ci descending => cols visited
    // in strictly decreasing order, so `>=` keeps the lowest index on ties.
    #pragma unroll
    for (int tn = 1; tn >= 0; --tn) {
      const float nwv = nw[tn];
      const int cidx = ncol + tn * 16 + l15;
      #pragma unroll
      for (int mt = 0; mt < 8; ++mt) {
        const f32x4 rvv = *(const f32x4*)&rrsh[mt * 16 + q * 4];
        #pragma unroll
        for (int reg = 0; reg < 4; ++reg) {
          const int s = mt * 4 + reg;
          float t1 = rvv[reg] + nwv;                   // fl(rr + |w|^2), as ref
          float v = fmaf(2.0f, acc[mt][tn][reg], -t1); // == fl(2*acc - t1)
          if (v >= bs[s]) { bs[s] = v; bi[s] = cidx; }
        }
      }
    }
  }

  // ---- block argmax reduction (overlay scratch on Ash) ----
  __syncthreads(); // all LDS A-reads complete
  float* red_s = (float*)Ash;      // [128][4]
  int* red_i = (int*)Ash + RB * 4; // [128][4]
  #pragma unroll
  for (int t = 0; t < 32; ++t) {
    float s = bs[t];
    int ii = bi[t];
    #pragma unroll
    for (int mask = 1; mask <= 8; mask <<= 1) {
      float os = __shfl_xor(s, mask, 64);
      int oi = __shfl_xor(ii, mask, 64);
      if (os > s || (os == s && oi < ii)) { s = os; ii = oi; }
    }
    if (l15 == 0) {
      const int rloc = (t >> 2) * 16 + q * 4 + (t & 3); // mt*16 + q*4 + reg
      red_s[rloc * 4 + wn] = s;
      red_i[rloc * 4 + wn] = ii;
    }
  }
  __syncthreads();
  if (tid < RB) {
    float s0 = red_s[tid * 4];
    int i0 = red_i[tid * 4];
    #pragma unroll
    for (int x = 1; x < 4; ++x) {
      float sx = red_s[tid * 4 + x];
      int ix = red_i[tid * 4 + x];
      if (sx > s0 || (sx == s0 && ix < i0)) { s0 = sx; i0 = ix; }
    }
    partial_s[(size_t)(rowBase + tid) * CS + cs] = s0;
    partial_i[(size_t)(rowBase + tid) * CS + cs] = i0;
  }
}

// ---------------------------------------------------------------------------
// Combine col-split partials -> code; resid -= W[c]; quantized += W[c];
// new rr; Aext row for next head.
__global__ __launch_bounds__(64) void reduce_update_kernel(const float* __restrict__ embh,
                                                           float* __restrict__ resid,
                                                           float* __restrict__ rr,
                                                           const float* __restrict__ ps,
                                                           const int* __restrict__ pi,
                                                           float* __restrict__ out,
                                                           _Float16* __restrict__ Aext, int h) {
  int row = blockIdx.x;
  int lane = threadIdx.x;
  float bs = -INFINITY;
  int bi = 0x7fffffff;
  if (lane < CS) {
    bs = ps[(size_t)row * CS + lane];
    bi = pi[(size_t)row * CS + lane];
  }
  #pragma unroll
  for (int m = 8; m; m >>= 1) {
    float os = __shfl_xor(bs, m, 64);
    int oi = __shfl_xor(bi, m, 64);
    if (os > bs || (os == bs && oi < bi)) { bs = os; bi = oi; }
  }
  int c = __shfl(bi, 0, 64);
  if (lane == 0) out[NB + NB * ND + row * NH + h] = (float)c; // codes as f32

  const float* wv = embh + (size_t)c * ND;
  float q0 = wv[lane], q1 = wv[lane + 64];
  float r0 = resid[row * ND + lane] - q0;
  float r1 = resid[row * ND + lane + 64] - q1;
  resid[row * ND + lane] = r0;
  resid[row * ND + lane + 64] = r1;
  out[NB + row * ND + lane] += q0;
  out[NB + row * ND + lane + 64] += q1;

  // Aext row for the next head (harmless extra work on the last head)
  _Float16 h0 = (_Float16)r0, l0 = (_Float16)(r0 - (float)h0);
  _Float16 h1 = (_Float16)r1, l1 = (_Float16)(r1 - (float)h1);
  _Float16* ab = Aext + (size_t)row * KA;
  ab[lane] = h0;       ab[lane + 64] = h1;       // rh
  ab[128 + lane] = l0; ab[128 + lane + 64] = l1; // rl

  float s = r0 * r0 + r1 * r1;
  #pragma unroll
  for (int m = 32; m; m >>= 1) s += __shfl_xor(s, m, 64);
  if (lane == 0) rr[row] = s;
}

// ---------------------------------------------------------------------------
extern "C" void kernel_launch(void* const* d_in, const int* in_sizes, int n_in,
                              void* d_out, int out_size, void* d_ws, size_t ws_size,
                              hipStream_t stream) {
  const float* inp = (const float*)d_in[0]; // (4096,1,128)
  const float* emb = (const float*)d_in[1]; // (3,32768,128)
  float* out = (float*)d_out;               // loss | quantized | codes

  float* resid = (float*)d_ws;                        // NB*ND f32
  float* rr = resid + NB * ND;                        // NB
  float* norms = rr + NB;                             // NH*NK
  float* ps = norms + NH * NK;                        // NB*CS f32
  int* pi = (int*)(ps + (size_t)NB * CS);             // NB*CS i32
  _Float16* Aext = (_Float16*)(pi + (size_t)NB * CS); // NB*KA f16
  _Float16* Bext = Aext + (size_t)NB * KA;            // NH*NK*KB f16 (~50 MB)

  hipLaunchKernelGGL(init_kernel, dim3(NB), dim3(64), 0, stream, inp, resid, rr, out, Aext);
  hipLaunchKernelGGL(norms_kernel, dim3(NH * NK / 4), dim3(256), 0, stream, emb, norms);
  hipLaunchKernelGGL(split_w_all_kernel, dim3(NH * NK / 16), dim3(256), 0, stream, emb, Bext);
  for (int h = 0; h < NH; ++h) {
    hipLaunchKernelGGL(score_mfma_kernel, dim3((NB / RB) * CS), dim3(256), 0, stream,
                       Aext, Bext + (size_t)h * NK * KB, rr, norms + (size_t)h * NK, ps, pi);
    hipLaunchKernelGGL(reduce_update_kernel, dim3(NB), dim3(64), 0, stream,
                       emb + (size_t)h * NK * ND, resid, rr, ps, pi, out, Aext, h);
  }
}

// Round 8
// 402.393 us; speedup vs baseline: 1.0492x; 1.0360x over previous
//
#include <hip/hip_runtime.h>
#include <math.h>

#define NB 4096
#define NH 3
#define NK 32768
#define ND 128
#define KA 256           // A stored K: [rh(128) | rl(128)]
#define KB 256           // B stored K: [wh(128) | wl(128)]  (dedup: wh read twice via regs)
#define RB 128           // rows per block (halves B amplification vs 64 at block level)
#define CS 16            // column splits (2 per XCD)
#define CPB (NK / CS)    // 2048 cols per block
#define CI 128           // cols per col-iteration (4 col-groups x 32)
#define NCI (CPB / CI)   // 16 col-iterations per block

typedef _Float16 half8_t __attribute__((ext_vector_type(8)));
typedef _Float16 half2_t __attribute__((ext_vector_type(2)));
typedef float f32x4 __attribute__((ext_vector_type(4)));
typedef __attribute__((address_space(1))) const unsigned int gu32_t;
typedef __attribute__((address_space(3))) unsigned int lu32_t;

// ---------------------------------------------------------------------------
// init: resid = inputs, quantized = 0, loss = 0, rr = sum(resid^2), Aext row.
__global__ __launch_bounds__(64) void init_kernel(const float* __restrict__ inp,
                                                  float* __restrict__ resid,
                                                  float* __restrict__ rr,
                                                  float* __restrict__ out,
                                                  _Float16* __restrict__ Aext) {
  int row = blockIdx.x;
  int lane = threadIdx.x;
  const float2* ip = (const float2*)(inp + row * ND);
  float2 v = ip[lane];
  ((float2*)(resid + row * ND))[lane] = v;
  ((float2*)(out + NB + row * ND))[lane] = make_float2(0.f, 0.f);
  if (lane == 0) out[row] = 0.f; // loss
  _Float16 h0 = (_Float16)v.x, h1 = (_Float16)v.y;
  _Float16 l0 = (_Float16)(v.x - (float)h0), l1 = (_Float16)(v.y - (float)h1);
  half2_t h = {h0, h1}, l = {l0, l1};
  _Float16* base = Aext + (size_t)row * KA;
  *(half2_t*)(base + 2 * lane) = h;       // rh
  *(half2_t*)(base + 128 + 2 * lane) = l; // rl
  float s = v.x * v.x + v.y * v.y;
  #pragma unroll
  for (int m = 32; m; m >>= 1) s += __shfl_xor(s, m, 64);
  if (lane == 0) rr[row] = s;
}

// ---------------------------------------------------------------------------
// norms[row] = sum(W[row]^2) for all H*K rows (one wave per row), fp32 exact.
// NOTE: do NOT change this reduction tree — its rounding order is what the
// reference-matching argmax ties were validated against.
__global__ __launch_bounds__(256) void norms_kernel(const float* __restrict__ emb,
                                                    float* __restrict__ norms) {
  int row = blockIdx.x * 4 + (threadIdx.x >> 6);
  int lane = threadIdx.x & 63;
  const float2* wp = (const float2*)(emb + (size_t)row * ND);
  float2 v = wp[lane];
  float s = v.x * v.x + v.y * v.y;
  #pragma unroll
  for (int m = 32; m; m >>= 1) s += __shfl_xor(s, m, 64);
  if (lane == 0) norms[row] = s;
}

// ---------------------------------------------------------------------------
// fp32 -> (hi,lo) fp16 split, ALL heads at once (emb is static), into
// kstep-major fragment layout WITHOUT the wh duplicate:
//   f16 offset = head*NK*KB + col64*16384 + ks*2048 + sub*512 + klo*128 + n_lo*8 + j
// ks 0..3 = wh chunks (k 0..127), ks 4..7 = wl chunks.
__global__ __launch_bounds__(256) void split_w_all_kernel(const float* __restrict__ emb,
                                                          _Float16* __restrict__ Bext) {
  const int head = blockIdx.x >> 11;      // 0..2
  const int cg = blockIdx.x & 2047;       // col group 0..2047 (16 cols each)
  const int n_lo = threadIdx.x & 15;
  const int c = threadIdx.x >> 4;         // 8-elem k-chunk 0..15 (k = c*8..)
  const int n = cg * 16 + n_lo;

  const float4* wp = (const float4*)(emb + (size_t)head * NK * ND + (size_t)n * ND + c * 8);
  float4 v0 = wp[0], v1 = wp[1];
  float xv[8] = {v0.x, v0.y, v0.z, v0.w, v1.x, v1.y, v1.z, v1.w};
  half8_t h, l;
  #pragma unroll
  for (int j = 0; j < 8; ++j) {
    _Float16 hh = (_Float16)xv[j];
    h[j] = hh;
    l[j] = (_Float16)(xv[j] - (float)hh);
  }
  const int ks0 = c >> 2; // 32-k chunk 0..3
  const int klo = c & 3;  // 8-chunk within the 32-k step
  _Float16* base = Bext + (size_t)head * NK * KB + (size_t)(cg >> 2) * 16384 +
                   (cg & 3) * 512 + klo * 128 + n_lo * 8;
  *(half8_t*)(base + ks0 * 2048) = h;       // wh  (ks 0..3)
  *(half8_t*)(base + (4 + ks0) * 2048) = l; // wl  (ks 4..7)
}

// ---------------------------------------------------------------------------
// Barrier-free score kernel — R8: 512-thread block, 8 waves of 64r x 32c
// (wr = wn>>2 row-half, wc = wn&3 col-group). Why: R7 measured 2 waves/SIMD
// (108 VGPR + 64 acc = 176 regs) with per-SIMD wall 15.4k cy/ci vs MFMA 7.4k
// — per-wave serial phases can't hide under only one other wave. Halving the
// per-wave tile halves acc (32) and bs/bi (32): ~112 regs peak -> 4 waves/
// SIMD via __launch_bounds__(512,4) [cap 512/4 = 128]. Grid 512 = 2 blocks/
// CU tail-free; LDS 2 x 64.5 KB = 129 <= 160. A-LDS pipe unchanged (~40%:
// A-reuse scales with cols/wave, kept at 32). Cost: B L2 traffic doubles to
// ~1 GB/dispatch (amp ~ 1/rows-per-wave) — streamable, L2-resident slice.
// Register discipline (R2/R4): acc DEAD at ci backedge (fold right after kc
// loop); A-frags read per-mt (8 transient); rr in LDS panel.
// Numerics byte-identical to the verified R0/R7 fold: ci desc + tn desc =>
// cols strictly decreasing, ">=" keeps lowest index (matches jnp.argmax).
// bid&15 = col-split; 2 x 1 MB B slices per XCD's L2 (cs mod 8 == xcd).
__global__ __launch_bounds__(512, 4) void score_mfma_kernel(
    const _Float16* __restrict__ Aext, const _Float16* __restrict__ Bext,
    const float* __restrict__ rr, const float* __restrict__ normh,
    float* __restrict__ partial_s, int* __restrict__ partial_i) {
  __shared__ __align__(16) _Float16 Ash[RB * KA]; // 64 KB: [p:4][m:128][slot:8][8 f16]
  __shared__ __align__(16) float rrsh[RB];        // 512 B

  const int bid = blockIdx.x;
  const int cs = bid & (CS - 1);
  const int rowb = bid >> 4;
  const int rowBase = rowb * RB;
  const int colBase0 = cs * CPB;

  const int tid = threadIdx.x;
  const int lane = tid & 63;
  const int wn = tid >> 6; // wave 0..7
  const int wc = wn & 3;   // col-group 0..3 (32 cols)
  const int wr = wn >> 2;  // row-half 0..1 (64 rows)
  const int l15 = lane & 15;
  const int q = lane >> 4;

  // ---- stage A panel [rh|rl] (once): wave wn stages 8 KB ----
  // LDS[p][m][slot] = A[rowBase+m][p*64 + (slot^(m&7))*8 ..+8]
  {
    const int p = wn >> 1;                  // panel 0..3 (64 k each)
    const int mh = (wn & 1) * 64;           // row half within panel
    const int mrow = lane >> 3;             // 0..7 within 8-row group
    const int cg = (lane & 7) ^ (mrow & 7); // global chunk this lane fetches
    #pragma unroll
    for (int i = 0; i < 8; ++i) {
      const int m0 = mh + i * 8; // 8-row group within the 128
      const _Float16* gA = Aext + (size_t)(rowBase + m0 + mrow) * KA + p * 64 + cg * 8;
      __builtin_amdgcn_global_load_lds((gu32_t*)gA, (lu32_t*)&Ash[(p * 128 + m0) * 64], 16, 0, 0);
    }
  }
  if (tid < RB) rrsh[tid] = rr[rowBase + tid];

  // per-lane A-fragment LDS byte addresses, even-kc parity (odd = ^64):
  // slot=(par*4+q)^(m&7); par flips byte bit6 carry-free (disjoint bits).
  int aaddr0[4];
  #pragma unroll
  for (int mt = 0; mt < 4; ++mt) {
    const int m = wr * 64 + mt * 16 + l15;
    const int slot = q ^ (m & 7);
    aaddr0[mt] = (m * 8 + slot) * 16; // bytes within a p-panel
  }

  float bs[16];
  int bi[16];
  #pragma unroll
  for (int t = 0; t < 16; ++t) { bs[t] = -INFINITY; bi[t] = 0x7fffffff; }

  __syncthreads(); // the only barrier before the epilogue

  #pragma unroll 1
  for (int ci = NCI - 1; ci >= 0; --ci) {
    const int ncol = colBase0 + ci * CI + wc * 32; // wave's 32-col tile
    const unsigned int boff = (unsigned int)(ncol >> 6) * 16384u +
                              ((unsigned int)(ncol >> 4) & 3u) * 512u +
                              (unsigned int)lane * 8u;

    // normh for this ci, issued early so they overlap the MFMA phase
    float nw[2];
    #pragma unroll
    for (int tn = 0; tn < 2; ++tn) nw[tn] = normh[ncol + tn * 16 + l15];

    f32x4 acc[4][2];
    #pragma unroll
    for (int i = 0; i < 4; ++i) {
      acc[i][0] = (f32x4){0.f, 0.f, 0.f, 0.f};
      acc[i][1] = (f32x4){0.f, 0.f, 0.f, 0.f};
    }

    #pragma unroll 2
    for (int kc = 0; kc < 4; ++kc) {
      half8_t bh[2], bl[2];
      #pragma unroll
      for (int tn = 0; tn < 2; ++tn) {
        bh[tn] = *(const half8_t*)(Bext + boff + (unsigned int)(kc * 2048 + tn * 512));
        bl[tn] = *(const half8_t*)(Bext + boff + (unsigned int)((4 + kc) * 2048 + tn * 512));
      }
      const int axor = (kc & 1) << 6;      // odd-kc slot parity
      const int abase = (kc >> 1) * 16384; // p-panel stride (128 rows x 128 B)
      __builtin_amdgcn_s_setprio(1); // T5: favor the MFMA-phase wave
      #pragma unroll
      for (int mt = 0; mt < 4; ++mt) {
        const char* ap = (const char*)Ash + ((aaddr0[mt] ^ axor) + abase);
        half8_t ah = *(const half8_t*)ap;           // rh frag
        half8_t al = *(const half8_t*)(ap + 32768); // rl frag (p+2 panels)
        acc[mt][0] = __builtin_amdgcn_mfma_f32_16x16x32_f16(ah, bh[0], acc[mt][0], 0, 0, 0);
        acc[mt][1] = __builtin_amdgcn_mfma_f32_16x16x32_f16(ah, bh[1], acc[mt][1], 0, 0, 0);
        acc[mt][0] = __builtin_amdgcn_mfma_f32_16x16x32_f16(al, bh[0], acc[mt][0], 0, 0, 0);
        acc[mt][1] = __builtin_amdgcn_mfma_f32_16x16x32_f16(al, bh[1], acc[mt][1], 0, 0, 0);
        acc[mt][0] = __builtin_amdgcn_mfma_f32_16x16x32_f16(ah, bl[0], acc[mt][0], 0, 0, 0);
        acc[mt][1] = __builtin_amdgcn_mfma_f32_16x16x32_f16(ah, bl[1], acc[mt][1], 0, 0, 0);
      }
      __builtin_amdgcn_s_setprio(0);
    }

    // fold into running argmax; tn DESCENDING + ci descending => cols visited
    // in strictly decreasing order, so `>=` keeps the lowest index on ties.
    #pragma unroll
    for (int tn = 1; tn >= 0; --tn) {
      const float nwv = nw[tn];
      const int cidx = ncol + tn * 16 + l15;
      #pragma unroll
      for (int mt = 0; mt < 4; ++mt) {
        const f32x4 rvv = *(const f32x4*)&rrsh[wr * 64 + mt * 16 + q * 4];
        #pragma unroll
        for (int reg = 0; reg < 4; ++reg) {
          const int s = mt * 4 + reg;
          float t1 = rvv[reg] + nwv;                   // fl(rr + |w|^2), as ref
          float v = fmaf(2.0f, acc[mt][tn][reg], -t1); // == fl(2*acc - t1)
          if (v >= bs[s]) { bs[s] = v; bi[s] = cidx; }
        }
      }
    }
  }

  // ---- block argmax reduction (overlay scratch on Ash) ----
  __syncthreads(); // all LDS A-reads complete
  float* red_s = (float*)Ash;      // [128][4]
  int* red_i = (int*)Ash + RB * 4; // [128][4]
  #pragma unroll
  for (int t = 0; t < 16; ++t) {
    float s = bs[t];
    int ii = bi[t];
    #pragma unroll
    for (int mask = 1; mask <= 8; mask <<= 1) {
      float os = __shfl_xor(s, mask, 64);
      int oi = __shfl_xor(ii, mask, 64);
      if (os > s || (os == s && oi < ii)) { s = os; ii = oi; }
    }
    if (l15 == 0) {
      // row slot: wr*64 + mt*16 + q*4 + reg; column lane wc
      const int rloc = wr * 64 + (t >> 2) * 16 + q * 4 + (t & 3);
      red_s[rloc * 4 + wc] = s;
      red_i[rloc * 4 + wc] = ii;
    }
  }
  __syncthreads();
  if (tid < RB) {
    float s0 = red_s[tid * 4];
    int i0 = red_i[tid * 4];
    #pragma unroll
    for (int x = 1; x < 4; ++x) {
      float sx = red_s[tid * 4 + x];
      int ix = red_i[tid * 4 + x];
      if (sx > s0 || (sx == s0 && ix < i0)) { s0 = sx; i0 = ix; }
    }
    partial_s[(size_t)(rowBase + tid) * CS + cs] = s0;
    partial_i[(size_t)(rowBase + tid) * CS + cs] = i0;
  }
}

// ---------------------------------------------------------------------------
// Combine col-split partials -> code; resid -= W[c]; quantized += W[c];
// new rr; Aext row for next head.
__global__ __launch_bounds__(64) void reduce_update_kernel(const float* __restrict__ embh,
                                                           float* __restrict__ resid,
                                                           float* __restrict__ rr,
                                                           const float* __restrict__ ps,
                                                           const int* __restrict__ pi,
                                                           float* __restrict__ out,
                                                           _Float16* __restrict__ Aext, int h) {
  int row = blockIdx.x;
  int lane = threadIdx.x;
  float bs = -INFINITY;
  int bi = 0x7fffffff;
  if (lane < CS) {
    bs = ps[(size_t)row * CS + lane];
    bi = pi[(size_t)row * CS + lane];
  }
  #pragma unroll
  for (int m = 8; m; m >>= 1) {
    float os = __shfl_xor(bs, m, 64);
    int oi = __shfl_xor(bi, m, 64);
    if (os > bs || (os == bs && oi < bi)) { bs = os; bi = oi; }
  }
  int c = __shfl(bi, 0, 64);
  if (lane == 0) out[NB + NB * ND + row * NH + h] = (float)c; // codes as f32

  const float* wv = embh + (size_t)c * ND;
  float q0 = wv[lane], q1 = wv[lane + 64];
  float r0 = resid[row * ND + lane] - q0;
  float r1 = resid[row * ND + lane + 64] - q1;
  resid[row * ND + lane] = r0;
  resid[row * ND + lane + 64] = r1;
  out[NB + row * ND + lane] += q0;
  out[NB + row * ND + lane + 64] += q1;

  // Aext row for the next head (harmless extra work on the last head)
  _Float16 h0 = (_Float16)r0, l0 = (_Float16)(r0 - (float)h0);
  _Float16 h1 = (_Float16)r1, l1 = (_Float16)(r1 - (float)h1);
  _Float16* ab = Aext + (size_t)row * KA;
  ab[lane] = h0;       ab[lane + 64] = h1;       // rh
  ab[128 + lane] = l0; ab[128 + lane + 64] = l1; // rl

  float s = r0 * r0 + r1 * r1;
  #pragma unroll
  for (int m = 32; m; m >>= 1) s += __shfl_xor(s, m, 64);
  if (lane == 0) rr[row] = s;
}

// ---------------------------------------------------------------------------
extern "C" void kernel_launch(void* const* d_in, const int* in_sizes, int n_in,
                              void* d_out, int out_size, void* d_ws, size_t ws_size,
                              hipStream_t stream) {
  const float* inp = (const float*)d_in[0]; // (4096,1,128)
  const float* emb = (const float*)d_in[1]; // (3,32768,128)
  float* out = (float*)d_out;               // loss | quantized | codes

  float* resid = (float*)d_ws;                        // NB*ND f32
  float* rr = resid + NB * ND;                        // NB
  float* norms = rr + NB;                             // NH*NK
  float* ps = norms + NH * NK;                        // NB*CS f32
  int* pi = (int*)(ps + (size_t)NB * CS);             // NB*CS i32
  _Float16* Aext = (_Float16*)(pi + (size_t)NB * CS); // NB*KA f16
  _Float16* Bext = Aext + (size_t)NB * KA;            // NH*NK*KB f16 (~50 MB)

  hipLaunchKernelGGL(init_kernel, dim3(NB), dim3(64), 0, stream, inp, resid, rr, out, Aext);
  hipLaunchKernelGGL(norms_kernel, dim3(NH * NK / 4), dim3(256), 0, stream, emb, norms);
  hipLaunchKernelGGL(split_w_all_kernel, dim3(NH * NK / 16), dim3(256), 0, stream, emb, Bext);
  for (int h = 0; h < NH; ++h) {
    hipLaunchKernelGGL(score_mfma_kernel, dim3((NB / RB) * CS), dim3(512), 0, stream,
                       Aext, Bext + (size_t)h * NK * KB, rr, norms + (size_t)h * NK, ps, pi);
    hipLaunchKernelGGL(reduce_update_kernel, dim3(NB), dim3(64), 0, stream,
                       emb + (size_t)h * NK * ND, resid, rr, ps, pi, out, Aext, h);
  }
}